// Round 10
// baseline (534.249 us; speedup 1.0000x reference)
//
#include <hip/hip_runtime.h>

#define BN 2
#define CH 256
#define HH 96
#define WW 96
#define NL 4
#define HW (HH*WW)        // 9216
#define KK (CH*9)         // 2304
#define NPOS (BN*HW)      // 18432

#define MPOS 32           // positions per block
#define NBLK (NPOS/MPOS)  // 576 blocks
#define CKCH 32           // channels per K-chunk
#define CKLEN (CKCH*9)    // 288 cols per chunk
#define SAMW2 296         // ushort row stride: 592 B

#define WB_PER_L (288*256*8)    // main weights bf16/layer
#define WB_TOT (NL*WB_PER_L)
#define OWB_PER_L (288*32*8)    // off weights bf16/layer (N padded to 32)
#define OWB_TOT (NL*OWB_PER_L)

typedef __attribute__((ext_vector_type(8))) short short8;
typedef __attribute__((ext_vector_type(4))) float f32x4;

__device__ __forceinline__ unsigned short f2bf(float f) {
    union { float f; unsigned int u; } v; v.f = f;
    unsigned int r = v.u + 0x7fffu + ((v.u >> 16) & 1u);
    return (unsigned short)(r >> 16);
}

// Pack dw -> wB and off_w -> owB (both bf16 B-frag order over permuted cols).
// Permuted column: col = ck*288 + t9*32 + ci, channel c = ck*32 + ci.
__global__ void prep_kernel(const float* __restrict__ dw, const float* __restrict__ off_w,
                            unsigned short* __restrict__ wB, unsigned short* __restrict__ owB) {
    int idx = blockIdx.x * 256 + threadIdx.x;
    if (idx < WB_TOT) {
        int j  = idx & 7;
        int oc = (idx >> 3) & 255;
        int g  = (idx >> 11) % 288;
        int l  = idx / WB_PER_L;
        int col = g * 8 + j;
        int ck = col / CKLEN;
        int r  = col - ck * CKLEN;
        int t9 = r >> 5;
        int ci = r & 31;
        int c  = ck * CKCH + ci;
        wB[idx] = f2bf(dw[((size_t)(l * CH + oc) * CH + c) * 9 + t9]);
    } else {
        int i2 = idx - WB_TOT;
        if (i2 >= OWB_TOT) return;
        int j   = i2 & 7;
        int ocp = (i2 >> 3) & 31;
        int g   = (i2 >> 8) % 288;
        int l   = i2 / OWB_PER_L;
        int col = g * 8 + j;
        int ck = col / CKLEN;
        int r  = col - ck * CKLEN;
        int t9 = r >> 5;
        int ci = r & 31;
        int c  = ck * CKCH + ci;
        owB[i2] = (ocp < 18) ? f2bf(off_w[((size_t)(l * 18 + ocp) * CH + c) * 9 + t9]) : 0;
    }
}

// Layer-0 only: NCHW f32 -> channel-last bf16 xT[b][hw][c].
__global__ void __launch_bounds__(256)
transpose_kernel(const float* __restrict__ src, unsigned short* __restrict__ xT) {
    __shared__ float tile[64][65];
    int blk = blockIdx.x;
    int b = blk / 576, r = blk - 576 * b;
    int hw0 = (r >> 2) * 64, c0 = (r & 3) * 64;
    int tid = threadIdx.x;
    int lane = tid & 63, grp = tid >> 6;
    const float* sp = src + (size_t)(b * CH + c0) * HW + hw0;
    #pragma unroll
    for (int i = 0; i < 16; ++i) {
        int c = grp * 16 + i;
        tile[c][lane] = sp[(size_t)c * HW + lane];
    }
    __syncthreads();
    unsigned short* dp = xT + (size_t)(b * HW + hw0) * CH + c0;
    #pragma unroll
    for (int i = 0; i < 16; ++i) {
        int hw = grp * 16 + i;
        dp[(size_t)hw * CH + lane] = f2bf(tile[lane][hw]);
    }
}

// One kernel = one whole layer for 32 positions: in-block offset-conv (MFMA,
// direct global A-frags), tap table, fused sampling + full-K MFMA GEMM,
// epilogue bias+relu writing bf16 channel-last xT (or f32 NCHW for last layer).
__global__ void __launch_bounds__(512)
layer_kernel(const unsigned short* __restrict__ xT, const unsigned short* __restrict__ owB,
             const float* __restrict__ ob, const unsigned short* __restrict__ wB,
             const float* __restrict__ db, unsigned short* __restrict__ xTo,
             float* __restrict__ outF, int last) {
    __shared__ __align__(16) unsigned short sam[MPOS * SAMW2];  // 18944 B (also offp, cT)
    __shared__ float offs[MPOS * 18];                           // 2304 B
    __shared__ __align__(16) uint4 taps4[MPOS * 9];             // 4608 B
    __shared__ unsigned short dso16[MPOS * 9];                  // 576 B
    __shared__ int rtab[MPOS * 9];                              // 1152 B
    const int tid = threadIdx.x;
    int pb = (int)blockIdx.x;
    pb = (pb & 7) * (NBLK / 8) + (pb >> 3);      // XCD swizzle
    const int pos0 = pb * MPOS;
    const int b0   = pos0 / HW;
    const int rem0 = pos0 - b0 * HW;
    const int h0   = rem0 / WW;
    const int w0   = rem0 - h0 * WW;

    // ---- phase 0: integer tap table for the offset conv ----
    for (int rec = tid; rec < MPOS * 9; rec += 512) {
        int p = rec / 9, t9 = rec - 9 * p;
        int dy = t9 / 3 - 1, dx = t9 - 3 * (t9 / 3) - 1;
        int y = h0 + dy, xw = w0 + p + dx;
        bool valid = ((unsigned)y < HH) && ((unsigned)xw < WW);
        rtab[rec] = valid ? (y * WW + xw) * CH : -1;
    }
    __syncthreads();

    const int m   = tid & 15;
    const int q   = (tid >> 4) & 3;
    const int wvi = tid >> 6;        // 0..7

    // ---- phase 1: offset conv. wave = (mt, ntq, kh) ----
    {
        const int mt  = wvi & 1;
        const int ntq = (wvi >> 1) & 1;
        const int kh  = wvi >> 2;
        const int p   = mt * 16 + m;
        const unsigned short* xq = xT + (size_t)b0 * HW * CH + q * 8;
        const unsigned short* wq = owB + (size_t)(ntq * 16 + m) * 8;
        f32x4 a0 = {}, a1 = {};
        for (int kb = 0; kb < 9; ++kb) {
            int s0 = rtab[p * 9 + kb];
            const unsigned short* ap = xq + s0;
            #pragma unroll
            for (int ckl = 0; ckl < 4; ++ckl) {
                int ck = kh * 4 + ckl;
                short8 av = {};
                if (s0 >= 0) av = *(const short8*)(ap + ck * CKCH);
                short8 bv = *(const short8*)(wq + (size_t)(ck * 36 + kb * 4 + q) * (32 * 8));
                if (ckl & 1) a1 = __builtin_amdgcn_mfma_f32_16x16x32_bf16(av, bv, a1, 0, 0, 0);
                else         a0 = __builtin_amdgcn_mfma_f32_16x16x32_bf16(av, bv, a0, 0, 0, 0);
            }
        }
        float* offp = (float*)sam;   // [kh][32][20] = 5120 B, overlays sam
        int oc = ntq * 16 + m;
        if (oc < 18) {
            #pragma unroll
            for (int r = 0; r < 4; ++r) {
                int pp = mt * 16 + q * 4 + r;
                offp[(kh * 32 + pp) * 20 + oc] = a0[r] + a1[r];
            }
        }
    }
    __syncthreads();
    for (int i = tid; i < MPOS * 18; i += 512) {
        int p = i / 18, oc = i - 18 * p;
        const float* offp = (const float*)sam;
        offs[i] = offp[p * 20 + oc] + offp[(32 + p) * 20 + oc] + ob[oc];
    }
    __syncthreads();

    // ---- phase 2: bilinear tap table ----
    for (int rec = tid; rec < MPOS * 9; rec += 512) {
        int p  = rec / 9, t9 = rec - 9 * p;
        int ky = t9 / 3, kx = t9 - 3 * (t9 / 3);
        float py = (float)(h0 - 1 + ky) + offs[p * 18 + 2 * t9];
        float px = (float)(w0 + p - 1 + kx) + offs[p * 18 + 2 * t9 + 1];
        float yf = floorf(py), xf = floorf(px);
        int y0 = (int)yf, x0 = (int)xf;
        float wy1 = py - yf, wx1 = px - xf;
        float fy0 = ((unsigned)y0       < HH) ? 1.f - wy1 : 0.f;
        float fy1 = ((unsigned)(y0 + 1) < HH) ? wy1       : 0.f;
        float fx0 = ((unsigned)x0       < WW) ? 1.f - wx1 : 0.f;
        float fx1 = ((unsigned)(x0 + 1) < WW) ? wx1       : 0.f;
        int y0c = min(max(y0, 0), HH - 1), y1c = min(max(y0 + 1, 0), HH - 1);
        int x0c = min(max(x0, 0), WW - 1), x1c = min(max(x0 + 1, 0), WW - 1);
        int bx  = min(max(x0, 0), WW - 2);
        float wA  = (x0c == bx     ? fx0 : 0.f) + (x1c == bx     ? fx1 : 0.f);
        float wBv = (x0c == bx + 1 ? fx0 : 0.f) + (x1c == bx + 1 ? fx1 : 0.f);
        uint4 tv;
        tv.x = (unsigned int)((y0c * WW + bx) * CH);
        tv.y = (unsigned int)((y1c * WW + bx) * CH);
        tv.z = (unsigned int)f2bf(fy0 * wA) | ((unsigned int)f2bf(fy0 * wBv) << 16);
        tv.w = (unsigned int)f2bf(fy1 * wA) | ((unsigned int)f2bf(fy1 * wBv) << 16);
        taps4[rec] = tv;
        dso16[rec] = (unsigned short)(p * SAMW2 + t9 * 32);
    }

    const int g   = tid >> 4;        // 0..31 sampling group
    const int cp  = tid & 15;        // channel pair
    const int mtg = wvi & 1;         // GEMM m-tile
    const int ntg = wvi >> 1;        // GEMM oc quarter (0..3)

    f32x4 acc[4] = {};
    const unsigned short* xTb = xT + (size_t)b0 * HW * CH;

    for (int ck = 0; ck < 8; ++ck) {
        __syncthreads();
        // ---- sampling: 288 records, 32 groups x 9 iterations ----
        const unsigned short* xs = xTb + ck * CKCH + cp * 2;
        #pragma unroll 3
        for (int it = 0; it < 9; ++it) {
            int rec = it * 32 + g;
            uint4 tv = taps4[rec];
            int dso  = dso16[rec];
            float u0 = __uint_as_float(tv.z << 16);
            float u1 = __uint_as_float(tv.z & 0xFFFF0000u);
            float u2 = __uint_as_float(tv.w << 16);
            float u3 = __uint_as_float(tv.w & 0xFFFF0000u);
            unsigned int A0, A1, C0, C1;
            __builtin_memcpy(&A0, xs + tv.x, 4);
            __builtin_memcpy(&A1, xs + tv.x + CH, 4);
            __builtin_memcpy(&C0, xs + tv.y, 4);
            __builtin_memcpy(&C1, xs + tv.y + CH, 4);
            float2 a0 = make_float2(__uint_as_float(A0 << 16), __uint_as_float(A0 & 0xFFFF0000u));
            float2 a1 = make_float2(__uint_as_float(A1 << 16), __uint_as_float(A1 & 0xFFFF0000u));
            float2 c0 = make_float2(__uint_as_float(C0 << 16), __uint_as_float(C0 & 0xFFFF0000u));
            float2 c1 = make_float2(__uint_as_float(C1 << 16), __uint_as_float(C1 & 0xFFFF0000u));
            float2 vv;
            vv.x = a0.x * u0;               vv.y = a0.y * u0;
            vv.x = fmaf(a1.x, u1, vv.x);    vv.y = fmaf(a1.y, u1, vv.y);
            vv.x = fmaf(c0.x, u2, vv.x);    vv.y = fmaf(c0.y, u2, vv.y);
            vv.x = fmaf(c1.x, u3, vv.x);    vv.y = fmaf(c1.y, u3, vv.y);
            unsigned int packed = (unsigned int)f2bf(vv.x) | ((unsigned int)f2bf(vv.y) << 16);
            *(unsigned int*)(sam + dso + cp * 2) = packed;
        }
        __syncthreads();
        // ---- GEMM: 9 k-tiles of 32; wave covers 16 pos x 64 oc ----
        const unsigned short* arow = sam + (mtg * 16 + m) * SAMW2 + q * 8;
        const int g0 = ck * 36;
        for (int kb = 0; kb < 9; ++kb) {
            short8 av = *(const short8*)(arow + kb * 32);
            const unsigned short* wkb = wB + ((size_t)(g0 + kb * 4 + q) * 256
                                             + (ntg * 64 + m)) * 8;
            #pragma unroll
            for (int t = 0; t < 4; ++t) {
                short8 bv = *(const short8*)(wkb + t * 16 * 8);
                acc[t] = __builtin_amdgcn_mfma_f32_16x16x32_bf16(av, bv, acc[t], 0, 0, 0);
            }
        }
    }

    // ---- epilogue: two 16-position passes through cT ----
    float* cT = (float*)sam;                 // [256][17] f32 = 17408 B
    #pragma unroll
    for (int pass = 0; pass < 2; ++pass) {
        __syncthreads();
        if (mtg == pass) {
            #pragma unroll
            for (int t = 0; t < 4; ++t) {
                int oc = ntg * 64 + t * 16 + m;
                #pragma unroll
                for (int r = 0; r < 4; ++r)
                    cT[oc * 17 + q * 4 + r] = acc[t][r];
            }
        }
        __syncthreads();
        if (!last) {
            int oc2 = (tid & 127) * 2;
            int pb4 = (tid >> 7) * 4;
            float bv0 = db[oc2], bv1 = db[oc2 + 1];
            unsigned short* dp = xTo + (size_t)(pos0 + pass * 16) * CH + oc2;
            #pragma unroll
            for (int j = 0; j < 4; ++j) {
                int p = pb4 + j;
                float v0 = fmaxf(cT[oc2 * 17 + p] + bv0, 0.f);
                float v1 = fmaxf(cT[(oc2 + 1) * 17 + p] + bv1, 0.f);
                unsigned int pk = (unsigned int)f2bf(v0) | ((unsigned int)f2bf(v1) << 16);
                *(unsigned int*)(dp + (size_t)p * CH) = pk;
            }
        } else {
            const int lane = tid & 63;
            const int po = lane & 15;
            const int os = lane >> 4;
            #pragma unroll
            for (int it = 0; it < 8; ++it) {
                int oc = wvi * 32 + it * 4 + os;
                float v = fmaxf(cT[oc * 17 + po] + db[oc], 0.f);
                outF[((size_t)(b0 * CH) + oc) * HW + rem0 + pass * 16 + po] = v;
            }
        }
    }
}

extern "C" void kernel_launch(void* const* d_in, const int* in_sizes, int n_in,
                              void* d_out, int out_size, void* d_ws, size_t ws_size,
                              hipStream_t stream) {
    const float* x     = (const float*)d_in[0];
    const float* off_w = (const float*)d_in[1];
    const float* off_b = (const float*)d_in[2];
    const float* dw    = (const float*)d_in[3];
    const float* db    = (const float*)d_in[4];

    unsigned short* xT0 = (unsigned short*)d_ws;             // NPOS*CH bf16
    unsigned short* xT1 = xT0 + (size_t)NPOS * CH;           // NPOS*CH bf16
    unsigned short* wB  = xT1 + (size_t)NPOS * CH;           // WB_TOT
    unsigned short* owB = wB + WB_TOT;                       // OWB_TOT

    prep_kernel<<<(WB_TOT + OWB_TOT + 255) / 256, 256, 0, stream>>>(dw, off_w, wB, owB);
    transpose_kernel<<<BN * 576, 256, 0, stream>>>(x, xT0);

    for (int l = 0; l < NL; ++l) {
        unsigned short* cur = (l & 1) ? xT1 : xT0;
        unsigned short* nxt = (l & 1) ? xT0 : xT1;
        layer_kernel<<<NBLK, 512, 0, stream>>>(
            cur, owB + (size_t)l * OWB_PER_L, off_b + l * 18,
            wB + (size_t)l * WB_PER_L, db + l * CH,
            nxt, (float*)d_out, (l == NL - 1) ? 1 : 0);
    }
}

// Round 11
// 487.962 us; speedup vs baseline: 1.0949x; 1.0949x over previous
//
#include <hip/hip_runtime.h>

#define BN 2
#define CH 256
#define HH 96
#define WW 96
#define NL 4
#define HW (HH*WW)        // 9216
#define KK (CH*9)         // 2304
#define NPOS (BN*HW)      // 18432

#define MPOS 32           // positions per block
#define NBLK (NPOS/MPOS)  // 576 position-blocks
#define CKCH 32           // channels per K-chunk
#define CKLEN (CKCH*9)    // 288 cols per chunk
#define NCKS 4            // chunks per split (split = 128 channels)
#define SAMW2 296         // ushort row stride: 592 B

#define WB_PER_L (288*256*8)    // main weights bf16/layer
#define WB_TOT (NL*WB_PER_L)
#define OWB_PER_L (288*32*8)    // off weights bf16/layer (N padded to 32)
#define OWB_TOT (NL*OWB_PER_L)

typedef __attribute__((ext_vector_type(8))) short short8;
typedef __attribute__((ext_vector_type(4))) float f32x4;

__device__ __forceinline__ unsigned short f2bf(float f) {
    union { float f; unsigned int u; } v; v.f = f;
    unsigned int r = v.u + 0x7fffu + ((v.u >> 16) & 1u);
    return (unsigned short)(r >> 16);
}

// Pack dw -> wB and off_w -> owB (both bf16 B-frag order over permuted cols).
// Permuted column: col = ck*288 + t9*32 + ci, channel c = ck*32 + ci.
__global__ void prep_kernel(const float* __restrict__ dw, const float* __restrict__ off_w,
                            unsigned short* __restrict__ wB, unsigned short* __restrict__ owB) {
    int idx = blockIdx.x * 256 + threadIdx.x;
    if (idx < WB_TOT) {
        int j  = idx & 7;
        int oc = (idx >> 3) & 255;
        int g  = (idx >> 11) % 288;
        int l  = idx / WB_PER_L;
        int col = g * 8 + j;
        int ck = col / CKLEN;
        int r  = col - ck * CKLEN;
        int t9 = r >> 5;
        int ci = r & 31;
        int c  = ck * CKCH + ci;
        wB[idx] = f2bf(dw[((size_t)(l * CH + oc) * CH + c) * 9 + t9]);
    } else {
        int i2 = idx - WB_TOT;
        if (i2 >= OWB_TOT) return;
        int j   = i2 & 7;
        int ocp = (i2 >> 3) & 31;
        int g   = (i2 >> 8) % 288;
        int l   = i2 / OWB_PER_L;
        int col = g * 8 + j;
        int ck = col / CKLEN;
        int r  = col - ck * CKLEN;
        int t9 = r >> 5;
        int ci = r & 31;
        int c  = ck * CKCH + ci;
        owB[i2] = (ocp < 18) ? f2bf(off_w[((size_t)(l * 18 + ocp) * CH + c) * 9 + t9]) : 0;
    }
}

// Layer-0 only: NCHW f32 -> channel-last bf16 xT[b][hw][c].
__global__ void __launch_bounds__(256)
transpose_kernel(const float* __restrict__ src, unsigned short* __restrict__ xT) {
    __shared__ float tile[64][65];
    int blk = blockIdx.x;
    int b = blk / 576, r = blk - 576 * b;
    int hw0 = (r >> 2) * 64, c0 = (r & 3) * 64;
    int tid = threadIdx.x;
    int lane = tid & 63, grp = tid >> 6;
    const float* sp = src + (size_t)(b * CH + c0) * HW + hw0;
    #pragma unroll
    for (int i = 0; i < 16; ++i) {
        int c = grp * 16 + i;
        tile[c][lane] = sp[(size_t)c * HW + lane];
    }
    __syncthreads();
    unsigned short* dp = xT + (size_t)(b * HW + hw0) * CH + c0;
    #pragma unroll
    for (int i = 0; i < 16; ++i) {
        int hw = grp * 16 + i;
        dp[(size_t)hw * CH + lane] = f2bf(tile[lane][hw]);
    }
}

// Split-K fused kernel: in-block offset conv (redundant per split, direct global
// A-frags, 4 waves = (mt,ntq) each full-K), bilinear tap table, fused sampling +
// MFMA GEMM on this split's 128 channels. Writes channel-last f32 partials.
__global__ void __launch_bounds__(256, 5)
deform_mfma_kernel(const unsigned short* __restrict__ xT, const unsigned short* __restrict__ owB,
                   const float* __restrict__ ob, const unsigned short* __restrict__ wB,
                   float* __restrict__ dst0, float* __restrict__ dst1) {
    __shared__ __align__(16) unsigned short sam[MPOS * SAMW2];  // 18944 B, reused as cT
    __shared__ float offs[MPOS * 18];                           // 2304 B
    __shared__ __align__(16) uint4 taps4[MPOS * 9];             // 4608 B
    __shared__ unsigned short dso16[MPOS * 9];                  // 576 B
    __shared__ int rtab[MPOS * 9];                              // 1152 B
    const int tid = threadIdx.x;
    const int s   = (int)blockIdx.x & 1;
    int pb = (int)blockIdx.x >> 1;
    pb = (pb & 7) * (NBLK / 8) + (pb >> 3);      // XCD swizzle
    const int pos0 = pb * MPOS;
    const int b0   = pos0 / HW;
    const int rem0 = pos0 - b0 * HW;
    const int h0   = rem0 / WW;
    const int w0   = rem0 - h0 * WW;

    // ---- phase 0: integer tap table for the offset conv ----
    for (int rec = tid; rec < MPOS * 9; rec += 256) {
        int p = rec / 9, t9 = rec - 9 * p;
        int dy = t9 / 3 - 1, dx = t9 - 3 * (t9 / 3) - 1;
        int y = h0 + dy, xw = w0 + p + dx;
        bool valid = ((unsigned)y < HH) && ((unsigned)xw < WW);
        rtab[rec] = valid ? (y * WW + xw) * CH : -1;
    }
    __syncthreads();

    const int m   = tid & 15;
    const int q   = (tid >> 4) & 3;
    const int wvi = tid >> 6;        // 0..3

    // ---- phase 1: offset conv. wave = (mt, ntq), full K, direct global A ----
    {
        const int mt  = wvi & 1;
        const int ntq = wvi >> 1;
        const int p   = mt * 16 + m;
        const unsigned short* xq = xT + (size_t)b0 * HW * CH + q * 8;
        const unsigned short* wq = owB + (size_t)(ntq * 16 + m) * 8;
        f32x4 a0 = {}, a1 = {};
        for (int kb = 0; kb < 9; ++kb) {
            int s0 = rtab[p * 9 + kb];
            const unsigned short* ap = xq + s0;
            #pragma unroll
            for (int ck = 0; ck < 8; ++ck) {
                short8 av = {};
                if (s0 >= 0) av = *(const short8*)(ap + ck * CKCH);
                short8 bv = *(const short8*)(wq + (size_t)(ck * 36 + kb * 4 + q) * (32 * 8));
                if (ck & 1) a1 = __builtin_amdgcn_mfma_f32_16x16x32_bf16(av, bv, a1, 0, 0, 0);
                else        a0 = __builtin_amdgcn_mfma_f32_16x16x32_bf16(av, bv, a0, 0, 0, 0);
            }
        }
        // D: row(pos) = q*4+r, col(oc) = m. Write final offs (bias folded).
        int oc = ntq * 16 + m;
        if (oc < 18) {
            float bsv = ob[oc];
            #pragma unroll
            for (int r = 0; r < 4; ++r) {
                int pp = mt * 16 + q * 4 + r;
                offs[pp * 18 + oc] = a0[r] + a1[r] + bsv;
            }
        }
    }
    __syncthreads();

    // ---- phase 2: bilinear tap table: 288 records, uint4 + ushort dso ----
    for (int rec = tid; rec < MPOS * 9; rec += 256) {
        int p  = rec / 9, t9 = rec - 9 * p;
        int ky = t9 / 3, kx = t9 - 3 * (t9 / 3);
        float py = (float)(h0 - 1 + ky) + offs[p * 18 + 2 * t9];
        float px = (float)(w0 + p - 1 + kx) + offs[p * 18 + 2 * t9 + 1];
        float yf = floorf(py), xf = floorf(px);
        int y0 = (int)yf, x0 = (int)xf;
        float wy1 = py - yf, wx1 = px - xf;
        float fy0 = ((unsigned)y0       < HH) ? 1.f - wy1 : 0.f;
        float fy1 = ((unsigned)(y0 + 1) < HH) ? wy1       : 0.f;
        float fx0 = ((unsigned)x0       < WW) ? 1.f - wx1 : 0.f;
        float fx1 = ((unsigned)(x0 + 1) < WW) ? wx1       : 0.f;
        int y0c = min(max(y0, 0), HH - 1), y1c = min(max(y0 + 1, 0), HH - 1);
        int x0c = min(max(x0, 0), WW - 1), x1c = min(max(x0 + 1, 0), WW - 1);
        int bx  = min(max(x0, 0), WW - 2);
        float wA  = (x0c == bx     ? fx0 : 0.f) + (x1c == bx     ? fx1 : 0.f);
        float wBv = (x0c == bx + 1 ? fx0 : 0.f) + (x1c == bx + 1 ? fx1 : 0.f);
        uint4 tv;
        tv.x = (unsigned int)((y0c * WW + bx) * CH);
        tv.y = (unsigned int)((y1c * WW + bx) * CH);
        tv.z = (unsigned int)f2bf(fy0 * wA) | ((unsigned int)f2bf(fy0 * wBv) << 16);
        tv.w = (unsigned int)f2bf(fy1 * wA) | ((unsigned int)f2bf(fy1 * wBv) << 16);
        taps4[rec] = tv;
        dso16[rec] = (unsigned short)(p * SAMW2 + t9 * 32);
    }

    const int lane = tid & 63;
    const int cp   = lane & 15;      // channel pair within chunk
    const int rsub = lane >> 4;      // record sub-slot

    f32x4 acc[2][4] = {};
    const unsigned short* xTb = xT + (size_t)b0 * HW * CH;

    for (int ckl = 0; ckl < NCKS; ++ckl) {
        const int ck = s * NCKS + ckl;
        __syncthreads();
        const unsigned short* xs = xTb + ck * CKCH + cp * 2;
        #pragma unroll 3
        for (int rr = 0; rr < 18; ++rr) {
            int rec = wvi * 72 + rr * 4 + rsub;
            uint4 tv = taps4[rec];
            int dso  = dso16[rec];
            float u0 = __uint_as_float(tv.z << 16);
            float u1 = __uint_as_float(tv.z & 0xFFFF0000u);
            float u2 = __uint_as_float(tv.w << 16);
            float u3 = __uint_as_float(tv.w & 0xFFFF0000u);
            unsigned int A0, A1, C0, C1;
            __builtin_memcpy(&A0, xs + tv.x, 4);
            __builtin_memcpy(&A1, xs + tv.x + CH, 4);
            __builtin_memcpy(&C0, xs + tv.y, 4);
            __builtin_memcpy(&C1, xs + tv.y + CH, 4);
            float2 a0 = make_float2(__uint_as_float(A0 << 16), __uint_as_float(A0 & 0xFFFF0000u));
            float2 a1 = make_float2(__uint_as_float(A1 << 16), __uint_as_float(A1 & 0xFFFF0000u));
            float2 c0 = make_float2(__uint_as_float(C0 << 16), __uint_as_float(C0 & 0xFFFF0000u));
            float2 c1 = make_float2(__uint_as_float(C1 << 16), __uint_as_float(C1 & 0xFFFF0000u));
            float2 vv;
            vv.x = a0.x * u0;               vv.y = a0.y * u0;
            vv.x = fmaf(a1.x, u1, vv.x);    vv.y = fmaf(a1.y, u1, vv.y);
            vv.x = fmaf(c0.x, u2, vv.x);    vv.y = fmaf(c0.y, u2, vv.y);
            vv.x = fmaf(c1.x, u3, vv.x);    vv.y = fmaf(c1.y, u3, vv.y);
            unsigned int packed = (unsigned int)f2bf(vv.x) | ((unsigned int)f2bf(vv.y) << 16);
            *(unsigned int*)(sam + dso + cp * 2) = packed;
        }
        __syncthreads();
        const unsigned short* arow0 = sam + m * SAMW2 + q * 8;
        const unsigned short* arow1 = arow0 + 16 * SAMW2;
        const int g0 = ck * 36;
        for (int kb = 0; kb < 9; ++kb) {
            short8 av0 = *(const short8*)(arow0 + kb * 32);
            short8 av1 = *(const short8*)(arow1 + kb * 32);
            const unsigned short* wkb = wB + ((size_t)(g0 + kb * 4 + q) * 256
                                             + (wvi * 64 + m)) * 8;
            #pragma unroll
            for (int t = 0; t < 4; ++t) {
                short8 bv = *(const short8*)(wkb + t * 16 * 8);
                acc[0][t] = __builtin_amdgcn_mfma_f32_16x16x32_bf16(av0, bv, acc[0][t], 0, 0, 0);
                acc[1][t] = __builtin_amdgcn_mfma_f32_16x16x32_bf16(av1, bv, acc[1][t], 0, 0, 0);
            }
        }
    }

    // ---- epilogue: channel-last partials pCL[pos][256] ----
    float* dst = s ? dst1 : dst0;
    float* cT = (float*)sam;                 // [256][17] f32 = 17408 B
    #pragma unroll
    for (int mt = 0; mt < 2; ++mt) {
        __syncthreads();
        #pragma unroll
        for (int t = 0; t < 4; ++t) {
            int oc = wvi * 64 + t * 16 + m;
            #pragma unroll
            for (int r = 0; r < 4; ++r)
                cT[oc * 17 + q * 4 + r] = acc[mt][t][r];
        }
        __syncthreads();
        float* dp = dst + (size_t)(pos0 + mt * 16) * CH + tid;
        #pragma unroll 4
        for (int p = 0; p < 16; ++p)
            dp[(size_t)p * CH] = cT[tid * 17 + p];
    }
}

// Layers 0-2 epilogue: xT = bf16(relu(p0 + p1 + bias)), channel-last (elementwise).
__global__ void __launch_bounds__(256)
sum_cl_kernel(const float* __restrict__ p0, const float* __restrict__ p1,
              const float* __restrict__ db, unsigned short* __restrict__ xT) {
    unsigned int idx = blockIdx.x * 256 + threadIdx.x;   // 4-elem group
    unsigned int e = idx * 4;
    unsigned int oc = e & (CH - 1);
    float4 bsv = *(const float4*)(db + oc);
    float4 a = *(const float4*)(p0 + e);
    float4 b = *(const float4*)(p1 + e);
    unsigned short o[4];
    o[0] = f2bf(fmaxf(a.x + b.x + bsv.x, 0.f));
    o[1] = f2bf(fmaxf(a.y + b.y + bsv.y, 0.f));
    o[2] = f2bf(fmaxf(a.z + b.z + bsv.z, 0.f));
    o[3] = f2bf(fmaxf(a.w + b.w + bsv.w, 0.f));
    __builtin_memcpy(xT + e, o, 8);
}

// Final layer epilogue: d_out(NCHW f32) = relu(p0 + p1 + bias), LDS transpose.
__global__ void __launch_bounds__(256)
sum_nchw_kernel(const float* __restrict__ p0, const float* __restrict__ p1,
                const float* __restrict__ db, float* __restrict__ out) {
    __shared__ float tile[64][65];
    int blk = blockIdx.x;
    int hw0 = (blk >> 2) * 64;            // flat pos base (never crosses batch)
    int oc0 = (blk & 3) * 64;
    int tid = threadIdx.x;
    int lane = tid & 63, grp = tid >> 6;
    float bsv = db[oc0 + lane];
    #pragma unroll
    for (int i = 0; i < 16; ++i) {
        int r = grp * 16 + i;
        size_t e = (size_t)(hw0 + r) * CH + oc0 + lane;
        tile[r][lane] = fmaxf(p0[e] + p1[e] + bsv, 0.f);
    }
    __syncthreads();
    int b = hw0 / HW, hwl = hw0 - b * HW;
    #pragma unroll
    for (int i = 0; i < 16; ++i) {
        int oc = grp * 16 + i;
        out[((size_t)(b * CH) + oc0 + oc) * HW + hwl + lane] = tile[lane][oc];
    }
}

extern "C" void kernel_launch(void* const* d_in, const int* in_sizes, int n_in,
                              void* d_out, int out_size, void* d_ws, size_t ws_size,
                              hipStream_t stream) {
    const float* x     = (const float*)d_in[0];
    const float* off_w = (const float*)d_in[1];
    const float* off_b = (const float*)d_in[2];
    const float* dw    = (const float*)d_in[3];
    const float* db    = (const float*)d_in[4];

    float* ws   = (float*)d_ws;
    float* p0    = ws;                                       // NPOS*CH f32
    float* p1    = p0 + (size_t)NPOS * CH;                   // NPOS*CH f32
    unsigned short* wB  = (unsigned short*)(p1 + (size_t)NPOS * CH);     // WB_TOT
    unsigned short* owB = wB + WB_TOT;                       // OWB_TOT
    unsigned short* xT  = owB + OWB_TOT;                     // NPOS*CH bf16

    prep_kernel<<<(WB_TOT + OWB_TOT + 255) / 256, 256, 0, stream>>>(dw, off_w, wB, owB);
    transpose_kernel<<<BN * 576, 256, 0, stream>>>(x, xT);

    for (int l = 0; l < NL; ++l) {
        deform_mfma_kernel<<<NBLK * 2, 256, 0, stream>>>(
            xT, owB + (size_t)l * OWB_PER_L, off_b + l * 18,
            wB + (size_t)l * WB_PER_L, p0, p1);
        if (l < NL - 1)
            sum_cl_kernel<<<(NPOS * CH / 4) / 256, 256, 0, stream>>>(p0, p1, db + l * CH, xT);
        else
            sum_nchw_kernel<<<(NPOS / 64) * 4, 256, 0, stream>>>(p0, p1, db + l * CH,
                                                                 (float*)d_out);
    }
}

// Round 12
// 433.202 us; speedup vs baseline: 1.2333x; 1.1264x over previous
//
#include <hip/hip_runtime.h>

#define BN 2
#define CH 256
#define HH 96
#define WW 96
#define NL 4
#define HW (HH*WW)        // 9216
#define KK (CH*9)         // 2304
#define NPOS (BN*HW)      // 18432

#define MPOS 32           // positions per block
#define NBLK (NPOS/MPOS)  // 576 position-blocks
#define CKCH 32           // channels per K-chunk
#define CKLEN (CKCH*9)    // 288 cols per chunk
#define NCKS 4            // chunks per deform split (split = 128 channels)
#define SAMW2 296         // ushort row stride: 592 B

#define WB_PER_L (288*256*8)    // main weights bf16/layer
#define WB_TOT (NL*WB_PER_L)
#define OWB_PER_L (288*32*8)    // off weights bf16/layer (N padded to 32)
#define OWB_TOT (NL*OWB_PER_L)

typedef __attribute__((ext_vector_type(8))) short short8;
typedef __attribute__((ext_vector_type(4))) float f32x4;

__device__ __forceinline__ unsigned short f2bf(float f) {
    union { float f; unsigned int u; } v; v.f = f;
    unsigned int r = v.u + 0x7fffu + ((v.u >> 16) & 1u);
    return (unsigned short)(r >> 16);
}

// Pack dw -> wB and off_w -> owB (both bf16 B-frag order over permuted cols).
// Permuted column: col = ck*288 + t9*32 + ci, channel c = ck*32 + ci.
__global__ void prep_kernel(const float* __restrict__ dw, const float* __restrict__ off_w,
                            unsigned short* __restrict__ wB, unsigned short* __restrict__ owB) {
    int idx = blockIdx.x * 256 + threadIdx.x;
    if (idx < WB_TOT) {
        int j  = idx & 7;
        int oc = (idx >> 3) & 255;
        int g  = (idx >> 11) % 288;
        int l  = idx / WB_PER_L;
        int col = g * 8 + j;
        int ck = col / CKLEN;
        int r  = col - ck * CKLEN;
        int t9 = r >> 5;
        int ci = r & 31;
        int c  = ck * CKCH + ci;
        wB[idx] = f2bf(dw[((size_t)(l * CH + oc) * CH + c) * 9 + t9]);
    } else {
        int i2 = idx - WB_TOT;
        if (i2 >= OWB_TOT) return;
        int j   = i2 & 7;
        int ocp = (i2 >> 3) & 31;
        int g   = (i2 >> 8) % 288;
        int l   = i2 / OWB_PER_L;
        int col = g * 8 + j;
        int ck = col / CKLEN;
        int r  = col - ck * CKLEN;
        int t9 = r >> 5;
        int ci = r & 31;
        int c  = ck * CKCH + ci;
        owB[i2] = (ocp < 18) ? f2bf(off_w[((size_t)(l * 18 + ocp) * CH + c) * 9 + t9]) : 0;
    }
}

// Layer-0 only: NCHW f32 -> channel-last bf16 xT[b][hw][c].
__global__ void __launch_bounds__(256)
transpose_kernel(const float* __restrict__ src, unsigned short* __restrict__ xT) {
    __shared__ float tile[64][65];
    int blk = blockIdx.x;
    int b = blk / 576, r = blk - 576 * b;
    int hw0 = (r >> 2) * 64, c0 = (r & 3) * 64;
    int tid = threadIdx.x;
    int lane = tid & 63, grp = tid >> 6;
    const float* sp = src + (size_t)(b * CH + c0) * HW + hw0;
    #pragma unroll
    for (int i = 0; i < 16; ++i) {
        int c = grp * 16 + i;
        tile[c][lane] = sp[(size_t)c * HW + lane];
    }
    __syncthreads();
    unsigned short* dp = xT + (size_t)(b * HW + hw0) * CH + c0;
    #pragma unroll
    for (int i = 0; i < 16; ++i) {
        int hw = grp * 16 + i;
        dp[(size_t)hw * CH + lane] = f2bf(tile[lane][hw]);
    }
}

// Offset conv, MFMA, direct global A-frags, K split 4 ways.
// bid = pb*4 + sp; split sp covers chunks {2sp, 2sp+1} (64 channels).
// Writes off_p[sp][pos][20] raw partials (no bias).
__global__ void __launch_bounds__(256)
off_mfma_kernel(const unsigned short* __restrict__ xT, const unsigned short* __restrict__ owB,
                float* __restrict__ off_p) {
    __shared__ int rtab[MPOS * 9];
    const int tid = threadIdx.x;
    const int sp  = (int)blockIdx.x & 3;
    int pb = (int)blockIdx.x >> 2;
    pb = (pb & 7) * (NBLK / 8) + (pb >> 3);      // XCD swizzle
    const int pos0 = pb * MPOS;
    const int b0   = pos0 / HW;
    const int rem0 = pos0 - b0 * HW;
    const int h0   = rem0 / WW;
    const int w0   = rem0 - h0 * WW;

    for (int rec = tid; rec < MPOS * 9; rec += 256) {
        int p = rec / 9, t9 = rec - 9 * p;
        int dy = t9 / 3 - 1, dx = t9 - 3 * (t9 / 3) - 1;
        int y = h0 + dy, xw = w0 + p + dx;
        bool valid = ((unsigned)y < HH) && ((unsigned)xw < WW);
        rtab[rec] = valid ? (y * WW + xw) * CH : -1;
    }
    __syncthreads();

    const int m   = tid & 15;
    const int q   = (tid >> 4) & 3;
    const int wvi = tid >> 6;
    const int mt  = wvi & 1;          // position-tile
    const int nt  = wvi >> 1;         // oc-tile
    const int p   = mt * 16 + m;      // this lane's A row = position

    const unsigned short* xq = xT + (size_t)b0 * HW * CH + q * 8;
    const unsigned short* wq = owB + (size_t)(nt * 16 + m) * 8;

    f32x4 acc0 = {}, acc1 = {};
    for (int kb = 0; kb < 9; ++kb) {
        int s0 = rtab[p * 9 + kb];
        const unsigned short* ap = xq + s0;
        #pragma unroll
        for (int ckl = 0; ckl < 2; ++ckl) {
            int ck = sp * 2 + ckl;
            short8 av = {};
            if (s0 >= 0) av = *(const short8*)(ap + ck * CKCH);
            short8 bv = *(const short8*)(wq + (size_t)(ck * 36 + kb * 4 + q) * (32 * 8));
            if (ckl & 1) acc1 = __builtin_amdgcn_mfma_f32_16x16x32_bf16(av, bv, acc1, 0, 0, 0);
            else         acc0 = __builtin_amdgcn_mfma_f32_16x16x32_bf16(av, bv, acc0, 0, 0, 0);
        }
    }
    // D: row(pos) = q*4+r, col(oc) = m
    int oc = nt * 16 + m;
    if (oc < 18) {
        float* op = off_p + (size_t)sp * NPOS * 20 + oc;
        #pragma unroll
        for (int r = 0; r < 4; ++r) {
            int pp = mt * 16 + q * 4 + r;
            op[(size_t)(pos0 + pp) * 20] = acc0[r] + acc1[r];
        }
    }
}

// Split-K fused sampling + MFMA. bid = pos-block*2 + split.
// Writes channel-last f32 partials pCL[pos][256].
__global__ void __launch_bounds__(256, 5)
deform_mfma_kernel(const unsigned short* __restrict__ xT, const float* __restrict__ off_p,
                   const float* __restrict__ ob, const unsigned short* __restrict__ wB,
                   float* __restrict__ dst0, float* __restrict__ dst1) {
    __shared__ __align__(16) unsigned short sam[MPOS * SAMW2];  // 18944 B, reused as cT
    __shared__ float offs[MPOS * 18];                           // 2304 B
    __shared__ __align__(16) uint4 taps4[MPOS * 9];             // 4608 B
    __shared__ unsigned short dso16[MPOS * 9];                  // 576 B
    const int tid = threadIdx.x;
    const int s   = (int)blockIdx.x & 1;
    int pb = (int)blockIdx.x >> 1;
    pb = (pb & 7) * (NBLK / 8) + (pb >> 3);      // XCD swizzle
    const int pos0 = pb * MPOS;
    const int b0   = pos0 / HW;
    const int rem0 = pos0 - b0 * HW;
    const int h0   = rem0 / WW;
    const int w0   = rem0 - h0 * WW;

    for (int i = tid; i < MPOS * 18; i += 256) {
        int p = i / 18, oc = i - 18 * p;
        const float* bp = off_p + (size_t)(pos0 + p) * 20 + oc;
        offs[i] = bp[0] + bp[(size_t)NPOS * 20] + bp[(size_t)NPOS * 40]
                + bp[(size_t)NPOS * 60] + ob[oc];
    }
    __syncthreads();

    // ---- tap table: 288 records, packed to one uint4 + ushort dso ----
    for (int rec = tid; rec < MPOS * 9; rec += 256) {
        int p  = rec / 9, t9 = rec - 9 * p;
        int ky = t9 / 3, kx = t9 - 3 * (t9 / 3);
        float py = (float)(h0 - 1 + ky) + offs[p * 18 + 2 * t9];
        float px = (float)(w0 + p - 1 + kx) + offs[p * 18 + 2 * t9 + 1];
        float yf = floorf(py), xf = floorf(px);
        int y0 = (int)yf, x0 = (int)xf;
        float wy1 = py - yf, wx1 = px - xf;
        float fy0 = ((unsigned)y0       < HH) ? 1.f - wy1 : 0.f;
        float fy1 = ((unsigned)(y0 + 1) < HH) ? wy1       : 0.f;
        float fx0 = ((unsigned)x0       < WW) ? 1.f - wx1 : 0.f;
        float fx1 = ((unsigned)(x0 + 1) < WW) ? wx1       : 0.f;
        int y0c = min(max(y0, 0), HH - 1), y1c = min(max(y0 + 1, 0), HH - 1);
        int x0c = min(max(x0, 0), WW - 1), x1c = min(max(x0 + 1, 0), WW - 1);
        int bx  = min(max(x0, 0), WW - 2);
        float wA  = (x0c == bx     ? fx0 : 0.f) + (x1c == bx     ? fx1 : 0.f);
        float wBv = (x0c == bx + 1 ? fx0 : 0.f) + (x1c == bx + 1 ? fx1 : 0.f);
        uint4 tv;
        tv.x = (unsigned int)((y0c * WW + bx) * CH);
        tv.y = (unsigned int)((y1c * WW + bx) * CH);
        tv.z = (unsigned int)f2bf(fy0 * wA) | ((unsigned int)f2bf(fy0 * wBv) << 16);
        tv.w = (unsigned int)f2bf(fy1 * wA) | ((unsigned int)f2bf(fy1 * wBv) << 16);
        taps4[rec] = tv;
        dso16[rec] = (unsigned short)(p * SAMW2 + t9 * 32);
    }

    const int lane = tid & 63;
    const int wvi  = tid >> 6;
    const int cp   = lane & 15;      // channel pair within chunk
    const int rsub = lane >> 4;      // record sub-slot
    const int m    = tid & 15;
    const int q    = (tid >> 4) & 3;

    f32x4 acc[2][4] = {};
    const unsigned short* xTb = xT + (size_t)b0 * HW * CH;

    for (int ckl = 0; ckl < NCKS; ++ckl) {
        const int ck = s * NCKS + ckl;
        __syncthreads();
        const unsigned short* xs = xTb + ck * CKCH + cp * 2;
        #pragma unroll 3
        for (int rr = 0; rr < 18; ++rr) {
            int rec = wvi * 72 + rr * 4 + rsub;
            uint4 tv = taps4[rec];
            int dso  = dso16[rec];
            float u0 = __uint_as_float(tv.z << 16);
            float u1 = __uint_as_float(tv.z & 0xFFFF0000u);
            float u2 = __uint_as_float(tv.w << 16);
            float u3 = __uint_as_float(tv.w & 0xFFFF0000u);
            unsigned int A0, A1, C0, C1;
            __builtin_memcpy(&A0, xs + tv.x, 4);
            __builtin_memcpy(&A1, xs + tv.x + CH, 4);
            __builtin_memcpy(&C0, xs + tv.y, 4);
            __builtin_memcpy(&C1, xs + tv.y + CH, 4);
            float2 a0 = make_float2(__uint_as_float(A0 << 16), __uint_as_float(A0 & 0xFFFF0000u));
            float2 a1 = make_float2(__uint_as_float(A1 << 16), __uint_as_float(A1 & 0xFFFF0000u));
            float2 c0 = make_float2(__uint_as_float(C0 << 16), __uint_as_float(C0 & 0xFFFF0000u));
            float2 c1 = make_float2(__uint_as_float(C1 << 16), __uint_as_float(C1 & 0xFFFF0000u));
            float2 vv;
            vv.x = a0.x * u0;               vv.y = a0.y * u0;
            vv.x = fmaf(a1.x, u1, vv.x);    vv.y = fmaf(a1.y, u1, vv.y);
            vv.x = fmaf(c0.x, u2, vv.x);    vv.y = fmaf(c0.y, u2, vv.y);
            vv.x = fmaf(c1.x, u3, vv.x);    vv.y = fmaf(c1.y, u3, vv.y);
            unsigned int packed = (unsigned int)f2bf(vv.x) | ((unsigned int)f2bf(vv.y) << 16);
            *(unsigned int*)(sam + dso + cp * 2) = packed;
        }
        __syncthreads();
        const unsigned short* arow0 = sam + m * SAMW2 + q * 8;
        const unsigned short* arow1 = arow0 + 16 * SAMW2;
        const int g0 = ck * 36;
        for (int kb = 0; kb < 9; ++kb) {
            short8 av0 = *(const short8*)(arow0 + kb * 32);
            short8 av1 = *(const short8*)(arow1 + kb * 32);
            const unsigned short* wkb = wB + ((size_t)(g0 + kb * 4 + q) * 256
                                             + (wvi * 64 + m)) * 8;
            #pragma unroll
            for (int t = 0; t < 4; ++t) {
                short8 bv = *(const short8*)(wkb + t * 16 * 8);
                acc[0][t] = __builtin_amdgcn_mfma_f32_16x16x32_bf16(av0, bv, acc[0][t], 0, 0, 0);
                acc[1][t] = __builtin_amdgcn_mfma_f32_16x16x32_bf16(av1, bv, acc[1][t], 0, 0, 0);
            }
        }
    }

    // ---- epilogue: channel-last partials pCL[pos][256] ----
    float* dst = s ? dst1 : dst0;
    float* cT = (float*)sam;                 // [256][17] f32 = 17408 B
    #pragma unroll
    for (int mt = 0; mt < 2; ++mt) {
        __syncthreads();
        #pragma unroll
        for (int t = 0; t < 4; ++t) {
            int oc = wvi * 64 + t * 16 + m;
            #pragma unroll
            for (int r = 0; r < 4; ++r)
                cT[oc * 17 + q * 4 + r] = acc[mt][t][r];
        }
        __syncthreads();
        float* dp = dst + (size_t)(pos0 + mt * 16) * CH + tid;
        #pragma unroll 4
        for (int p = 0; p < 16; ++p)
            dp[(size_t)p * CH] = cT[tid * 17 + p];
    }
}

// Layers 0-2 epilogue: xT = bf16(relu(p0 + p1 + bias)), channel-last (elementwise).
__global__ void __launch_bounds__(256)
sum_cl_kernel(const float* __restrict__ p0, const float* __restrict__ p1,
              const float* __restrict__ db, unsigned short* __restrict__ xT) {
    unsigned int idx = blockIdx.x * 256 + threadIdx.x;   // 4-elem group
    unsigned int e = idx * 4;
    unsigned int oc = e & (CH - 1);
    float4 bsv = *(const float4*)(db + oc);
    float4 a = *(const float4*)(p0 + e);
    float4 b = *(const float4*)(p1 + e);
    unsigned short o[4];
    o[0] = f2bf(fmaxf(a.x + b.x + bsv.x, 0.f));
    o[1] = f2bf(fmaxf(a.y + b.y + bsv.y, 0.f));
    o[2] = f2bf(fmaxf(a.z + b.z + bsv.z, 0.f));
    o[3] = f2bf(fmaxf(a.w + b.w + bsv.w, 0.f));
    __builtin_memcpy(xT + e, o, 8);
}

// Final layer epilogue: d_out(NCHW f32) = relu(p0 + p1 + bias), LDS transpose.
__global__ void __launch_bounds__(256)
sum_nchw_kernel(const float* __restrict__ p0, const float* __restrict__ p1,
                const float* __restrict__ db, float* __restrict__ out) {
    __shared__ float tile[64][65];
    int blk = blockIdx.x;
    int hw0 = (blk >> 2) * 64;            // flat pos base (never crosses batch)
    int oc0 = (blk & 3) * 64;
    int tid = threadIdx.x;
    int lane = tid & 63, grp = tid >> 6;
    float bsv = db[oc0 + lane];
    #pragma unroll
    for (int i = 0; i < 16; ++i) {
        int r = grp * 16 + i;
        size_t e = (size_t)(hw0 + r) * CH + oc0 + lane;
        tile[r][lane] = fmaxf(p0[e] + p1[e] + bsv, 0.f);
    }
    __syncthreads();
    int b = hw0 / HW, hwl = hw0 - b * HW;
    #pragma unroll
    for (int i = 0; i < 16; ++i) {
        int oc = grp * 16 + i;
        out[((size_t)(b * CH) + oc0 + oc) * HW + hwl + lane] = tile[lane][oc];
    }
}

extern "C" void kernel_launch(void* const* d_in, const int* in_sizes, int n_in,
                              void* d_out, int out_size, void* d_ws, size_t ws_size,
                              hipStream_t stream) {
    const float* x     = (const float*)d_in[0];
    const float* off_w = (const float*)d_in[1];
    const float* off_b = (const float*)d_in[2];
    const float* dw    = (const float*)d_in[3];
    const float* db    = (const float*)d_in[4];

    float* ws   = (float*)d_ws;
    float* p0    = ws;                                       // NPOS*CH f32
    float* p1    = p0 + (size_t)NPOS * CH;                   // NPOS*CH f32
    float* off_p = p1 + (size_t)NPOS * CH;                   // 4*NPOS*20 f32
    unsigned short* wB  = (unsigned short*)(off_p + (size_t)4 * NPOS * 20);  // WB_TOT
    unsigned short* owB = wB + WB_TOT;                       // OWB_TOT
    unsigned short* xT  = owB + OWB_TOT;                     // NPOS*CH bf16

    prep_kernel<<<(WB_TOT + OWB_TOT + 255) / 256, 256, 0, stream>>>(dw, off_w, wB, owB);
    transpose_kernel<<<BN * 576, 256, 0, stream>>>(x, xT);

    for (int l = 0; l < NL; ++l) {
        off_mfma_kernel<<<NBLK * 4, 256, 0, stream>>>(
            xT, owB + (size_t)l * OWB_PER_L, off_p);
        deform_mfma_kernel<<<NBLK * 2, 256, 0, stream>>>(
            xT, off_p, off_b + l * 18, wB + (size_t)l * WB_PER_L, p0, p1);
        if (l < NL - 1)
            sum_cl_kernel<<<(NPOS * CH / 4) / 256, 256, 0, stream>>>(p0, p1, db + l * CH, xT);
        else
            sum_nchw_kernel<<<(NPOS / 64) * 4, 256, 0, stream>>>(p0, p1, db + l * CH,
                                                                 (float*)d_out);
    }
}

// Round 13
// 411.408 us; speedup vs baseline: 1.2986x; 1.0530x over previous
//
#include <hip/hip_runtime.h>
#include <hip/hip_bf16.h>

#define BN 2
#define CH 256
#define HH 96
#define WW 96
#define NL 4
#define HW (HH*WW)        // 9216
#define KK (CH*9)         // 2304
#define NPOS (BN*HW)      // 18432

#define MPOS 32           // positions per block
#define NBLK (NPOS/MPOS)  // 576 position-blocks
#define CKCH 32           // channels per K-chunk
#define CKLEN (CKCH*9)    // 288 cols per chunk
#define NCKS 4            // chunks per deform split (split = 128 channels)
#define SAMW2 296         // ushort row stride: 592 B

#define WB_PER_L (288*256*8)    // main weights bf16/layer
#define WB_TOT (NL*WB_PER_L)
#define OWB_PER_L (288*32*8)    // off weights bf16/layer (N padded to 32)
#define OWB_TOT (NL*OWB_PER_L)

typedef __attribute__((ext_vector_type(8))) short short8;
typedef __attribute__((ext_vector_type(4))) float f32x4;

__device__ __forceinline__ unsigned short f2bf(float f) {
    union { float f; unsigned int u; } v; v.f = f;
    unsigned int r = v.u + 0x7fffu + ((v.u >> 16) & 1u);
    return (unsigned short)(r >> 16);
}
__device__ __forceinline__ unsigned int pack_bf2(float lo, float hi) {
    float2 t; t.x = lo; t.y = hi;
    __hip_bfloat162 hb = __float22bfloat162_rn(t);   // RNE, packed cvt on gfx950
    unsigned int u; __builtin_memcpy(&u, &hb, 4);
    return u;
}

// Pack dw -> wB and off_w -> owB (both bf16 B-frag order over permuted cols),
// and zero the CH-element zero-row at xT[NPOS*CH] (invalid-tap target).
// Permuted column: col = ck*288 + t9*32 + ci, channel c = ck*32 + ci.
__global__ void prep_kernel(const float* __restrict__ dw, const float* __restrict__ off_w,
                            unsigned short* __restrict__ wB, unsigned short* __restrict__ owB,
                            unsigned short* __restrict__ xT) {
    int idx = blockIdx.x * 256 + threadIdx.x;
    if (idx < WB_TOT) {
        int j  = idx & 7;
        int oc = (idx >> 3) & 255;
        int g  = (idx >> 11) % 288;
        int l  = idx / WB_PER_L;
        int col = g * 8 + j;
        int ck = col / CKLEN;
        int r  = col - ck * CKLEN;
        int t9 = r >> 5;
        int ci = r & 31;
        int c  = ck * CKCH + ci;
        wB[idx] = f2bf(dw[((size_t)(l * CH + oc) * CH + c) * 9 + t9]);
    } else if (idx < WB_TOT + OWB_TOT) {
        int i2 = idx - WB_TOT;
        int j   = i2 & 7;
        int ocp = (i2 >> 3) & 31;
        int g   = (i2 >> 8) % 288;
        int l   = i2 / OWB_PER_L;
        int col = g * 8 + j;
        int ck = col / CKLEN;
        int r  = col - ck * CKLEN;
        int t9 = r >> 5;
        int ci = r & 31;
        int c  = ck * CKCH + ci;
        owB[i2] = (ocp < 18) ? f2bf(off_w[((size_t)(l * 18 + ocp) * CH + c) * 9 + t9]) : 0;
    } else if (idx < WB_TOT + OWB_TOT + CH) {
        xT[(size_t)NPOS * CH + (idx - WB_TOT - OWB_TOT)] = 0;
    }
}

// Layer-0 only: NCHW f32 -> channel-last bf16 xT[b][hw][c].
__global__ void __launch_bounds__(256)
transpose_kernel(const float* __restrict__ src, unsigned short* __restrict__ xT) {
    __shared__ float tile[64][65];
    int blk = blockIdx.x;
    int b = blk / 576, r = blk - 576 * b;
    int hw0 = (r >> 2) * 64, c0 = (r & 3) * 64;
    int tid = threadIdx.x;
    int lane = tid & 63, grp = tid >> 6;
    const float* sp = src + (size_t)(b * CH + c0) * HW + hw0;
    #pragma unroll
    for (int i = 0; i < 16; ++i) {
        int c = grp * 16 + i;
        tile[c][lane] = sp[(size_t)c * HW + lane];
    }
    __syncthreads();
    unsigned short* dp = xT + (size_t)(b * HW + hw0) * CH + c0;
    #pragma unroll
    for (int i = 0; i < 16; ++i) {
        int hw = grp * 16 + i;
        dp[(size_t)hw * CH + lane] = f2bf(tile[lane][hw]);
    }
}

// Offset conv, MFMA, direct global A-frags, K split 4 ways, fully unrolled and
// branch-free (invalid taps read the zero-row), letting the compiler pipeline
// all 18 loads ahead of the MFMA chain.
// bid = pb*4 + sp; split sp covers chunks {2sp, 2sp+1} (64 channels).
// Writes off_p[sp][pos][20] raw partials (no bias).
__global__ void __launch_bounds__(256)
off_mfma_kernel(const unsigned short* __restrict__ xT, const unsigned short* __restrict__ owB,
                float* __restrict__ off_p) {
    __shared__ int rtab[MPOS * 9];
    const int tid = threadIdx.x;
    const int sp  = (int)blockIdx.x & 3;
    int pb = (int)blockIdx.x >> 2;
    pb = (pb & 7) * (NBLK / 8) + (pb >> 3);      // XCD swizzle
    const int pos0 = pb * MPOS;
    const int b0   = pos0 / HW;
    const int rem0 = pos0 - b0 * HW;
    const int h0   = rem0 / WW;
    const int w0   = rem0 - h0 * WW;
    const int zrel = (NPOS - b0 * HW) * CH;      // zero-row, relative to xTb

    for (int rec = tid; rec < MPOS * 9; rec += 256) {
        int p = rec / 9, t9 = rec - 9 * p;
        int dy = t9 / 3 - 1, dx = t9 - 3 * (t9 / 3) - 1;
        int y = h0 + dy, xw = w0 + p + dx;
        bool valid = ((unsigned)y < HH) && ((unsigned)xw < WW);
        rtab[rec] = valid ? (y * WW + xw) * CH : zrel;
    }
    __syncthreads();

    const int m   = tid & 15;
    const int q   = (tid >> 4) & 3;
    const int wvi = tid >> 6;
    const int mt  = wvi & 1;          // position-tile
    const int nt  = wvi >> 1;         // oc-tile
    const int p   = mt * 16 + m;      // this lane's A row = position

    int s0[9];
    #pragma unroll
    for (int kb = 0; kb < 9; ++kb) s0[kb] = rtab[p * 9 + kb];

    const unsigned short* xq = xT + (size_t)b0 * HW * CH + q * 8 + (size_t)sp * 2 * CKCH;
    const unsigned short* wq = owB + (size_t)(nt * 16 + m) * 8
                                   + (size_t)(sp * 2 * 36 + q) * (32 * 8);

    f32x4 acc0 = {}, acc1 = {};
    #pragma unroll
    for (int kb = 0; kb < 9; ++kb) {
        short8 av0 = *(const short8*)(xq + s0[kb]);
        short8 av1 = *(const short8*)(xq + s0[kb] + CKCH);
        short8 bv0 = *(const short8*)(wq + (size_t)(kb * 4) * (32 * 8));
        short8 bv1 = *(const short8*)(wq + (size_t)(36 + kb * 4) * (32 * 8));
        acc0 = __builtin_amdgcn_mfma_f32_16x16x32_bf16(av0, bv0, acc0, 0, 0, 0);
        acc1 = __builtin_amdgcn_mfma_f32_16x16x32_bf16(av1, bv1, acc1, 0, 0, 0);
    }
    // D: row(pos) = q*4+r, col(oc) = m
    int oc = nt * 16 + m;
    if (oc < 18) {
        float* op = off_p + (size_t)sp * NPOS * 20 + oc;
        #pragma unroll
        for (int r = 0; r < 4; ++r) {
            int pp = mt * 16 + q * 4 + r;
            op[(size_t)(pos0 + pp) * 20] = acc0[r] + acc1[r];
        }
    }
}

// Split-K fused sampling + MFMA. bid = pos-block*2 + split.
// Writes channel-last f32 partials pCL[pos][256].
__global__ void __launch_bounds__(256, 5)
deform_mfma_kernel(const unsigned short* __restrict__ xT, const float* __restrict__ off_p,
                   const float* __restrict__ ob, const unsigned short* __restrict__ wB,
                   float* __restrict__ dst0, float* __restrict__ dst1) {
    __shared__ __align__(16) unsigned short sam[MPOS * SAMW2];  // 18944 B, reused as cT
    __shared__ float offs[MPOS * 18];                           // 2304 B
    __shared__ __align__(16) uint4 taps4[MPOS * 9];             // 4608 B
    __shared__ unsigned short dso16[MPOS * 9];                  // 576 B
    const int tid = threadIdx.x;
    const int s   = (int)blockIdx.x & 1;
    int pb = (int)blockIdx.x >> 1;
    pb = (pb & 7) * (NBLK / 8) + (pb >> 3);      // XCD swizzle
    const int pos0 = pb * MPOS;
    const int b0   = pos0 / HW;
    const int rem0 = pos0 - b0 * HW;
    const int h0   = rem0 / WW;
    const int w0   = rem0 - h0 * WW;

    for (int i = tid; i < MPOS * 18; i += 256) {
        int p = i / 18, oc = i - 18 * p;
        const float* bp = off_p + (size_t)(pos0 + p) * 20 + oc;
        offs[i] = bp[0] + bp[(size_t)NPOS * 20] + bp[(size_t)NPOS * 40]
                + bp[(size_t)NPOS * 60] + ob[oc];
    }
    __syncthreads();

    // ---- tap table: 288 records, packed to one uint4 + ushort dso ----
    for (int rec = tid; rec < MPOS * 9; rec += 256) {
        int p  = rec / 9, t9 = rec - 9 * p;
        int ky = t9 / 3, kx = t9 - 3 * (t9 / 3);
        float py = (float)(h0 - 1 + ky) + offs[p * 18 + 2 * t9];
        float px = (float)(w0 + p - 1 + kx) + offs[p * 18 + 2 * t9 + 1];
        float yf = floorf(py), xf = floorf(px);
        int y0 = (int)yf, x0 = (int)xf;
        float wy1 = py - yf, wx1 = px - xf;
        float fy0 = ((unsigned)y0       < HH) ? 1.f - wy1 : 0.f;
        float fy1 = ((unsigned)(y0 + 1) < HH) ? wy1       : 0.f;
        float fx0 = ((unsigned)x0       < WW) ? 1.f - wx1 : 0.f;
        float fx1 = ((unsigned)(x0 + 1) < WW) ? wx1       : 0.f;
        int y0c = min(max(y0, 0), HH - 1), y1c = min(max(y0 + 1, 0), HH - 1);
        int x0c = min(max(x0, 0), WW - 1), x1c = min(max(x0 + 1, 0), WW - 1);
        int bx  = min(max(x0, 0), WW - 2);
        float wA  = (x0c == bx     ? fx0 : 0.f) + (x1c == bx     ? fx1 : 0.f);
        float wBv = (x0c == bx + 1 ? fx0 : 0.f) + (x1c == bx + 1 ? fx1 : 0.f);
        uint4 tv;
        tv.x = (unsigned int)((y0c * WW + bx) * CH);
        tv.y = (unsigned int)((y1c * WW + bx) * CH);
        tv.z = pack_bf2(fy0 * wA, fy0 * wBv);
        tv.w = pack_bf2(fy1 * wA, fy1 * wBv);
        taps4[rec] = tv;
        dso16[rec] = (unsigned short)(p * SAMW2 + t9 * 32);
    }

    const int lane = tid & 63;
    const int wvi  = tid >> 6;
    const int cp   = lane & 15;      // channel pair within chunk
    const int rsub = lane >> 4;      // record sub-slot
    const int m    = tid & 15;
    const int q    = (tid >> 4) & 3;

    f32x4 acc[2][4] = {};
    const unsigned short* xTb = xT + (size_t)b0 * HW * CH;

    for (int ckl = 0; ckl < NCKS; ++ckl) {
        const int ck = s * NCKS + ckl;
        __syncthreads();
        const unsigned short* xs = xTb + ck * CKCH + cp * 2;
        #pragma unroll 3
        for (int rr = 0; rr < 18; ++rr) {
            int rec = wvi * 72 + rr * 4 + rsub;
            uint4 tv = taps4[rec];
            int dso  = dso16[rec];
            float u0 = __uint_as_float(tv.z << 16);
            float u1 = __uint_as_float(tv.z & 0xFFFF0000u);
            float u2 = __uint_as_float(tv.w << 16);
            float u3 = __uint_as_float(tv.w & 0xFFFF0000u);
            unsigned int A0, A1, C0, C1;
            __builtin_memcpy(&A0, xs + tv.x, 4);
            __builtin_memcpy(&A1, xs + tv.x + CH, 4);
            __builtin_memcpy(&C0, xs + tv.y, 4);
            __builtin_memcpy(&C1, xs + tv.y + CH, 4);
            float2 a0 = make_float2(__uint_as_float(A0 << 16), __uint_as_float(A0 & 0xFFFF0000u));
            float2 a1 = make_float2(__uint_as_float(A1 << 16), __uint_as_float(A1 & 0xFFFF0000u));
            float2 c0 = make_float2(__uint_as_float(C0 << 16), __uint_as_float(C0 & 0xFFFF0000u));
            float2 c1 = make_float2(__uint_as_float(C1 << 16), __uint_as_float(C1 & 0xFFFF0000u));
            float2 vv;
            vv.x = a0.x * u0;               vv.y = a0.y * u0;
            vv.x = fmaf(a1.x, u1, vv.x);    vv.y = fmaf(a1.y, u1, vv.y);
            vv.x = fmaf(c0.x, u2, vv.x);    vv.y = fmaf(c0.y, u2, vv.y);
            vv.x = fmaf(c1.x, u3, vv.x);    vv.y = fmaf(c1.y, u3, vv.y);
            *(unsigned int*)(sam + dso + cp * 2) = pack_bf2(vv.x, vv.y);
        }
        __syncthreads();
        const unsigned short* arow0 = sam + m * SAMW2 + q * 8;
        const unsigned short* arow1 = arow0 + 16 * SAMW2;
        const int g0 = ck * 36;
        for (int kb = 0; kb < 9; ++kb) {
            short8 av0 = *(const short8*)(arow0 + kb * 32);
            short8 av1 = *(const short8*)(arow1 + kb * 32);
            const unsigned short* wkb = wB + ((size_t)(g0 + kb * 4 + q) * 256
                                             + (wvi * 64 + m)) * 8;
            #pragma unroll
            for (int t = 0; t < 4; ++t) {
                short8 bv = *(const short8*)(wkb + t * 16 * 8);
                acc[0][t] = __builtin_amdgcn_mfma_f32_16x16x32_bf16(av0, bv, acc[0][t], 0, 0, 0);
                acc[1][t] = __builtin_amdgcn_mfma_f32_16x16x32_bf16(av1, bv, acc[1][t], 0, 0, 0);
            }
        }
    }

    // ---- epilogue: channel-last partials pCL[pos][256] ----
    float* dst = s ? dst1 : dst0;
    float* cT = (float*)sam;                 // [256][17] f32 = 17408 B
    #pragma unroll
    for (int mt = 0; mt < 2; ++mt) {
        __syncthreads();
        #pragma unroll
        for (int t = 0; t < 4; ++t) {
            int oc = wvi * 64 + t * 16 + m;
            #pragma unroll
            for (int r = 0; r < 4; ++r)
                cT[oc * 17 + q * 4 + r] = acc[mt][t][r];
        }
        __syncthreads();
        float* dp = dst + (size_t)(pos0 + mt * 16) * CH + tid;
        #pragma unroll 4
        for (int p = 0; p < 16; ++p)
            dp[(size_t)p * CH] = cT[tid * 17 + p];
    }
}

// Layers 0-2 epilogue: xT = bf16(relu(p0 + p1 + bias)), channel-last (elementwise).
__global__ void __launch_bounds__(256)
sum_cl_kernel(const float* __restrict__ p0, const float* __restrict__ p1,
              const float* __restrict__ db, unsigned short* __restrict__ xT) {
    unsigned int idx = blockIdx.x * 256 + threadIdx.x;   // 4-elem group
    unsigned int e = idx * 4;
    unsigned int oc = e & (CH - 1);
    float4 bsv = *(const float4*)(db + oc);
    float4 a = *(const float4*)(p0 + e);
    float4 b = *(const float4*)(p1 + e);
    unsigned int o2[2];
    o2[0] = pack_bf2(fmaxf(a.x + b.x + bsv.x, 0.f), fmaxf(a.y + b.y + bsv.y, 0.f));
    o2[1] = pack_bf2(fmaxf(a.z + b.z + bsv.z, 0.f), fmaxf(a.w + b.w + bsv.w, 0.f));
    __builtin_memcpy(xT + e, o2, 8);
}

// Final layer epilogue: d_out(NCHW f32) = relu(p0 + p1 + bias), LDS transpose.
__global__ void __launch_bounds__(256)
sum_nchw_kernel(const float* __restrict__ p0, const float* __restrict__ p1,
                const float* __restrict__ db, float* __restrict__ out) {
    __shared__ float tile[64][65];
    int blk = blockIdx.x;
    int hw0 = (blk >> 2) * 64;            // flat pos base (never crosses batch)
    int oc0 = (blk & 3) * 64;
    int tid = threadIdx.x;
    int lane = tid & 63, grp = tid >> 6;
    float bsv = db[oc0 + lane];
    #pragma unroll
    for (int i = 0; i < 16; ++i) {
        int r = grp * 16 + i;
        size_t e = (size_t)(hw0 + r) * CH + oc0 + lane;
        tile[r][lane] = fmaxf(p0[e] + p1[e] + bsv, 0.f);
    }
    __syncthreads();
    int b = hw0 / HW, hwl = hw0 - b * HW;
    #pragma unroll
    for (int i = 0; i < 16; ++i) {
        int oc = grp * 16 + i;
        out[((size_t)(b * CH) + oc0 + oc) * HW + hwl + lane] = tile[lane][oc];
    }
}

extern "C" void kernel_launch(void* const* d_in, const int* in_sizes, int n_in,
                              void* d_out, int out_size, void* d_ws, size_t ws_size,
                              hipStream_t stream) {
    const float* x     = (const float*)d_in[0];
    const float* off_w = (const float*)d_in[1];
    const float* off_b = (const float*)d_in[2];
    const float* dw    = (const float*)d_in[3];
    const float* db    = (const float*)d_in[4];

    float* ws   = (float*)d_ws;
    float* p0    = ws;                                       // NPOS*CH f32
    float* p1    = p0 + (size_t)NPOS * CH;                   // NPOS*CH f32
    float* off_p = p1 + (size_t)NPOS * CH;                   // 4*NPOS*20 f32
    unsigned short* wB  = (unsigned short*)(off_p + (size_t)4 * NPOS * 20);  // WB_TOT
    unsigned short* owB = wB + WB_TOT;                       // OWB_TOT
    unsigned short* xT  = owB + OWB_TOT;                     // NPOS*CH bf16 + CH zero-row

    prep_kernel<<<(WB_TOT + OWB_TOT + CH + 255) / 256, 256, 0, stream>>>(
        dw, off_w, wB, owB, xT);
    transpose_kernel<<<BN * 576, 256, 0, stream>>>(x, xT);

    for (int l = 0; l < NL; ++l) {
        off_mfma_kernel<<<NBLK * 4, 256, 0, stream>>>(
            xT, owB + (size_t)l * OWB_PER_L, off_p);
        deform_mfma_kernel<<<NBLK * 2, 256, 0, stream>>>(
            xT, off_p, off_b + l * 18, wB + (size_t)l * WB_PER_L, p0, p1);
        if (l < NL - 1)
            sum_cl_kernel<<<(NPOS * CH / 4) / 256, 256, 0, stream>>>(p0, p1, db + l * CH, xT);
        else
            sum_nchw_kernel<<<(NPOS / 64) * 4, 256, 0, stream>>>(p0, p1, db + l * CH,
                                                                 (float*)d_out);
    }
}